// Round 1
// 207.089 us; speedup vs baseline: 1.0363x; 1.0363x over previous
//
#include <hip/hip_runtime.h>
#include <hip/hip_fp16.h>

#define N_NODES 100000
#define F_IN 128
#define H 16
#define NBIN 391           // ceil(N_NODES/256); bin b owns nodes [b*256, b*256+256)
#define BINCAP 4608        // per-bin record capacity (mean 4096, +8 sigma)
#define ECHUNK 8192        // edges per binfill block (512 thr x 16)
#define QSCALE 4096.0f     // int16 fixed-point scale (range ±8, err 1.2e-4)
#define QINV (1.0f / 4096.0f)

// sign-extend packed int16 halves
#define SXL(u) (((int)((u) << 16)) >> 16)
#define SXH(u) (((int)(u)) >> 16)

// Pack two floats to int16 fixed-point (round-nearest, clamped)
__device__ inline unsigned int packi16(float a, float b) {
  int ia = __float2int_rn(fminf(fmaxf(a * QSCALE, -32767.f), 32767.f));
  int ib = __float2int_rn(fminf(fmaxf(b * QSCALE, -32767.f), 32767.f));
  return (unsigned int)((ia & 0xffff) | (ib << 16));
}

// ---------------------------------------------------------------------------
// k_init: binCur[b] = b * BINCAP  (record-region cursors)
// ---------------------------------------------------------------------------
__global__ void __launch_bounds__(512) k_init(int* __restrict__ binCur) {
  int t = threadIdx.x;
  if (t < NBIN) binCur[t] = t * BINCAP;
}

// ---------------------------------------------------------------------------
// k_lin1 (v4, split-K=4): y1l = i16fx(x @ W1l), y1r = x @ W1r (fp32).
// 256 thr = 4 waves x 64 nodes; wave w handles K-quarter w (wave-uniform ->
// W scalar-loaded, K$-resident -> FMA-bound). x read exactly once.
// Waves 1-3 write partials to LDS; wave 0 reduces in FIXED source order
// ((p0+p1)+p2)+p3 -> bitwise deterministic.
// ---------------------------------------------------------------------------
__global__ void __launch_bounds__(256) k_lin1(
    const float* __restrict__ x, const float* __restrict__ W1l,
    const float* __restrict__ W1r, unsigned short* __restrict__ y1l,
    float* __restrict__ y1r) {
  __shared__ float red[3 * 32 * 64];   // 24 KB: [part-1][ch 0..31][node 0..63]
  int t = threadIdx.x;
  int part = __builtin_amdgcn_readfirstlane(t >> 6);   // wave index 0..3
  int ln = t & 63;
  int n = blockIdx.x * 64 + ln;
  int nc = (n < N_NODES) ? n : (N_NODES - 1);          // clamp; stores guarded
  const float4* xr = (const float4*)(x + (size_t)nc * F_IN + part * (F_IN / 4));
  float4 xv[8];
#pragma unroll
  for (int j = 0; j < 8; ++j) xv[j] = xr[j];
  const float* Wl = W1l + part * (F_IN / 4) * H;       // SGPR base, 2 KB
  const float* Wr = W1r + part * (F_IN / 4) * H;       // SGPR base, 2 KB
  float al[H], ar[H];
#pragma unroll
  for (int c = 0; c < H; ++c) { al[c] = 0.f; ar[c] = 0.f; }
#pragma unroll
  for (int j = 0; j < 8; ++j) {
    float xs[4] = {xv[j].x, xv[j].y, xv[j].z, xv[j].w};
#pragma unroll
    for (int jj = 0; jj < 4; ++jj) {
      int k = j * 4 + jj;
#pragma unroll
      for (int c = 0; c < H; ++c) {
        al[c] = fmaf(xs[jj], Wl[k * H + c], al[c]);
        ar[c] = fmaf(xs[jj], Wr[k * H + c], ar[c]);
      }
    }
  }
  if (part != 0) {
    int base = (part - 1) * 2048;
#pragma unroll
    for (int c = 0; c < H; ++c) {
      red[base + c * 64 + ln] = al[c];
      red[base + (H + c) * 64 + ln] = ar[c];
    }
  }
  __syncthreads();
  if (part == 0 && n < N_NODES) {
#pragma unroll
    for (int c = 0; c < H; ++c) {
      al[c] = ((al[c] + red[c * 64 + ln]) + red[2048 + c * 64 + ln])
              + red[4096 + c * 64 + ln];
      ar[c] = ((ar[c] + red[(H + c) * 64 + ln]) + red[2048 + (H + c) * 64 + ln])
              + red[4096 + (H + c) * 64 + ln];
    }
    uint4 w0, w1;
    w0.x = packi16(al[0], al[1]);  w0.y = packi16(al[2], al[3]);
    w0.z = packi16(al[4], al[5]);  w0.w = packi16(al[6], al[7]);
    w1.x = packi16(al[8], al[9]);  w1.y = packi16(al[10], al[11]);
    w1.z = packi16(al[12], al[13]); w1.w = packi16(al[14], al[15]);
    uint4* ol = (uint4*)(y1l + (size_t)n * H);   // 32 B row
    ol[0] = w0;
    ol[1] = w1;
    float4* orr = (float4*)(y1r + (size_t)n * H);
#pragma unroll
    for (int q = 0; q < 4; ++q)
      orr[q] = make_float4(ar[4 * q], ar[4 * q + 1], ar[4 * q + 2], ar[4 * q + 3]);
  }
}

// ---------------------------------------------------------------------------
// k_binfill: radix pass — bin records (src<<8 | dstLow) by dst>>8.
// 512 thr x 16 edges -> 196 blocks -> 77k per-(block,bin) reservation atomics.
// Record ORDER is nondeterministic; record SET is deterministic — downstream
// accumulation is integer (order-invariant), so this is fine. Records are
// ONLY binned, never sorted: the per-bin LDS-atomic aggregation kernels
// below don't need per-node contiguous lists.
// ---------------------------------------------------------------------------
__global__ void __launch_bounds__(512) k_binfill(
    const int* __restrict__ src, const int* __restrict__ dst,
    int* __restrict__ binCur, int* __restrict__ recs, int E) {
  __shared__ int hist[512];
  __shared__ int gbase[512];
  __shared__ int cnt2[512];
  int t = threadIdx.x;
  hist[t] = 0;
  cnt2[t] = 0;
  __syncthreads();
  int base = blockIdx.x * ECHUNK;
  int rec[16], bin[16];
#pragma unroll
  for (int j = 0; j < 16; ++j) {
    int e = base + j * 512 + t;
    if (e < E) {
      int s = src[e];
      int d = dst[e];
      rec[j] = (s << 8) | (d & 255);
      bin[j] = d >> 8;
      atomicAdd(&hist[bin[j]], 1);
    } else {
      bin[j] = -1;
    }
  }
  __syncthreads();
  if (t < NBIN) {
    int c = hist[t];
    gbase[t] = (c > 0) ? atomicAdd(&binCur[t], c) : 0;
  }
  __syncthreads();
#pragma unroll
  for (int j = 0; j < 16; ++j) {
    if (bin[j] >= 0) {
      int loc = atomicAdd(&cnt2[bin[j]], 1);
      int slot = gbase[bin[j]] + loc;
      if (slot < (bin[j] + 1) * BINCAP)  // safety clamp (never expected)
        recs[slot] = rec[j];
    }
  }
}

// ---------------------------------------------------------------------------
// k_agg1: per-bin edge-parallel conv1 aggregation + epilogue.
// One block per bin (391 x 512 thr). Streams the bin's records (coalesced),
// gathers y1l[src] (32B, L2-resident), and accumulates into LDS
// acc[ch][node] int32 via ds-atomics (deterministic, order-invariant).
// Layout [ch][nodeLow]: bank = node%32 -> random ~2-way conflicts (free).
// Degree = LDS counter (replaces deg/rowBeg arrays + k_group entirely;
// every record is exactly one lane-task -> no divergence stretch).
// Epilogue: h1 = relu(mean + b1 + y1r) -> LDS; z2 = h1 @ W2{l,r} with W2
// staged in LDS (wave-uniform broadcast reads). Per-channel FMA order over
// k = 0..15 matches the previous version bit-for-bit.
// ---------------------------------------------------------------------------
__global__ void __launch_bounds__(512) k_agg1(
    const int* __restrict__ recs, const int* __restrict__ binCur,
    const unsigned short* __restrict__ y1l, const float* __restrict__ y1r,
    const float* __restrict__ b1, const float* __restrict__ W2l,
    const float* __restrict__ W2r, unsigned short* __restrict__ z2l,
    float* __restrict__ z2r) {
  __shared__ int acc[16][256];     // 16 KB
  __shared__ int cnt[256];         // 1 KB
  __shared__ float hf[16][256];    // 16 KB (h1, [ch][node])
  __shared__ float w2l[256];       // 1 KB
  __shared__ float w2r[256];       // 1 KB
  int t = threadIdx.x;
  int b = blockIdx.x;
#pragma unroll
  for (int j = 0; j < 8; ++j) ((int*)acc)[j * 512 + t] = 0;
  if (t < 256) { cnt[t] = 0; w2l[t] = W2l[t]; }
  else         w2r[t - 256] = W2r[t - 256];
  __syncthreads();
  int rbase = b * BINCAP;
  int R = binCur[b] - rbase;
  if (R > BINCAP) R = BINCAP;
  int rr[9];
#pragma unroll
  for (int j = 0; j < 9; ++j) {
    int idx = j * 512 + t;
    rr[j] = (idx < R) ? recs[rbase + idx] : -1;
  }
  uint4 va[9], vb[9];
#pragma unroll
  for (int j = 0; j < 9; ++j) {
    int s = (rr[j] >= 0) ? (rr[j] >> 8) : 0;
    const uint4* yp = (const uint4*)(y1l + (size_t)s * H);
    va[j] = yp[0];
    vb[j] = yp[1];
  }
#pragma unroll
  for (int j = 0; j < 9; ++j) {
    if (rr[j] >= 0) {
      int nb = rr[j] & 255;
      uint4 v0 = va[j], v1 = vb[j];
      atomicAdd(&cnt[nb], 1);
      atomicAdd(&acc[0][nb],  SXL(v0.x)); atomicAdd(&acc[1][nb],  SXH(v0.x));
      atomicAdd(&acc[2][nb],  SXL(v0.y)); atomicAdd(&acc[3][nb],  SXH(v0.y));
      atomicAdd(&acc[4][nb],  SXL(v0.z)); atomicAdd(&acc[5][nb],  SXH(v0.z));
      atomicAdd(&acc[6][nb],  SXL(v0.w)); atomicAdd(&acc[7][nb],  SXH(v0.w));
      atomicAdd(&acc[8][nb],  SXL(v1.x)); atomicAdd(&acc[9][nb],  SXH(v1.x));
      atomicAdd(&acc[10][nb], SXL(v1.y)); atomicAdd(&acc[11][nb], SXH(v1.y));
      atomicAdd(&acc[12][nb], SXL(v1.z)); atomicAdd(&acc[13][nb], SXH(v1.z));
      atomicAdd(&acc[14][nb], SXL(v1.w)); atomicAdd(&acc[15][nb], SXH(v1.w));
    }
  }
  __syncthreads();
  // ---- epilogue: thread (node = t>>1, half = t&1) owns 8 channels ----
  int node = t >> 1;
  int half = t & 1;
  int coff = half * 8;
  int n = (b << 8) + node;
  if (n < N_NODES) {
    float s = QINV / fmaxf((float)cnt[node], 1.f);
    const float4* yrp = (const float4*)(y1r + (size_t)n * H + coff);
    float4 y0 = yrp[0], y1v = yrp[1];
    const float4* bp = (const float4*)(b1 + coff);
    float4 b0 = bp[0], b1v = bp[1];
    float yv[8] = {y0.x, y0.y, y0.z, y0.w, y1v.x, y1v.y, y1v.z, y1v.w};
    float bv[8] = {b0.x, b0.y, b0.z, b0.w, b1v.x, b1v.y, b1v.z, b1v.w};
#pragma unroll
    for (int c = 0; c < 8; ++c) {
      float h = fmaf((float)acc[coff + c][node], s, bv[c] + yv[c]);
      hf[coff + c][node] = fmaxf(h, 0.f);
    }
  } else {
#pragma unroll
    for (int c = 0; c < 8; ++c) hf[coff + c][node] = 0.f;
  }
  __syncthreads();
  float zl[8], zr[8];
#pragma unroll
  for (int c = 0; c < 8; ++c) { zl[c] = 0.f; zr[c] = 0.f; }
#pragma unroll
  for (int k = 0; k < 16; ++k) {
    float hk = hf[k][node];
#pragma unroll
    for (int c = 0; c < 8; ++c) {
      zl[c] = fmaf(hk, w2l[k * 16 + coff + c], zl[c]);
      zr[c] = fmaf(hk, w2r[k * 16 + coff + c], zr[c]);
    }
  }
  if (n < N_NODES) {
    uint4 pk;
    pk.x = packi16(zl[0], zl[1]);
    pk.y = packi16(zl[2], zl[3]);
    pk.z = packi16(zl[4], zl[5]);
    pk.w = packi16(zl[6], zl[7]);
    *(uint4*)(z2l + (size_t)n * H + coff) = pk;
    float4* zp = (float4*)(z2r + (size_t)n * H + coff);
    zp[0] = make_float4(zr[0], zr[1], zr[2], zr[3]);
    zp[1] = make_float4(zr[4], zr[5], zr[6], zr[7]);
  }
}

// ---------------------------------------------------------------------------
// k_agg2: per-bin edge-parallel conv2 aggregation.
// h2 = fp16(mean(z2l_nbrs) + b2 + z2r). Same structure as k_agg1.
// ---------------------------------------------------------------------------
__global__ void __launch_bounds__(512) k_agg2(
    const int* __restrict__ recs, const int* __restrict__ binCur,
    const unsigned short* __restrict__ z2l, const float* __restrict__ z2r,
    const float* __restrict__ b2, __half* __restrict__ h2) {
  __shared__ int acc[16][256];
  __shared__ int cnt[256];
  int t = threadIdx.x;
  int b = blockIdx.x;
#pragma unroll
  for (int j = 0; j < 8; ++j) ((int*)acc)[j * 512 + t] = 0;
  if (t < 256) cnt[t] = 0;
  __syncthreads();
  int rbase = b * BINCAP;
  int R = binCur[b] - rbase;
  if (R > BINCAP) R = BINCAP;
  int rr[9];
#pragma unroll
  for (int j = 0; j < 9; ++j) {
    int idx = j * 512 + t;
    rr[j] = (idx < R) ? recs[rbase + idx] : -1;
  }
  uint4 va[9], vb[9];
#pragma unroll
  for (int j = 0; j < 9; ++j) {
    int s = (rr[j] >= 0) ? (rr[j] >> 8) : 0;
    const uint4* yp = (const uint4*)(z2l + (size_t)s * H);
    va[j] = yp[0];
    vb[j] = yp[1];
  }
#pragma unroll
  for (int j = 0; j < 9; ++j) {
    if (rr[j] >= 0) {
      int nb = rr[j] & 255;
      uint4 v0 = va[j], v1 = vb[j];
      atomicAdd(&cnt[nb], 1);
      atomicAdd(&acc[0][nb],  SXL(v0.x)); atomicAdd(&acc[1][nb],  SXH(v0.x));
      atomicAdd(&acc[2][nb],  SXL(v0.y)); atomicAdd(&acc[3][nb],  SXH(v0.y));
      atomicAdd(&acc[4][nb],  SXL(v0.z)); atomicAdd(&acc[5][nb],  SXH(v0.z));
      atomicAdd(&acc[6][nb],  SXL(v0.w)); atomicAdd(&acc[7][nb],  SXH(v0.w));
      atomicAdd(&acc[8][nb],  SXL(v1.x)); atomicAdd(&acc[9][nb],  SXH(v1.x));
      atomicAdd(&acc[10][nb], SXL(v1.y)); atomicAdd(&acc[11][nb], SXH(v1.y));
      atomicAdd(&acc[12][nb], SXL(v1.z)); atomicAdd(&acc[13][nb], SXH(v1.z));
      atomicAdd(&acc[14][nb], SXL(v1.w)); atomicAdd(&acc[15][nb], SXH(v1.w));
    }
  }
  __syncthreads();
  int node = t >> 1;
  int half = t & 1;
  int coff = half * 8;
  int n = (b << 8) + node;
  if (n < N_NODES) {
    float s = QINV / fmaxf((float)cnt[node], 1.f);
    const float4* zrp = (const float4*)(z2r + (size_t)n * H + coff);
    float4 z0 = zrp[0], z1 = zrp[1];
    const float4* bp = (const float4*)(b2 + coff);
    float4 b0 = bp[0], b1v = bp[1];
    float zv[8] = {z0.x, z0.y, z0.z, z0.w, z1.x, z1.y, z1.z, z1.w};
    float bv[8] = {b0.x, b0.y, b0.z, b0.w, b1v.x, b1v.y, b1v.z, b1v.w};
    float v[8];
#pragma unroll
    for (int c = 0; c < 8; ++c)
      v[c] = fmaf((float)acc[coff + c][node], s, bv[c] + zv[c]);
    __half2 h0 = __floats2half2_rn(v[0], v[1]);
    __half2 h1 = __floats2half2_rn(v[2], v[3]);
    __half2 h2p = __floats2half2_rn(v[4], v[5]);
    __half2 h3 = __floats2half2_rn(v[6], v[7]);
    uint4 pk;
    pk.x = *(unsigned int*)&h0;
    pk.y = *(unsigned int*)&h1;
    pk.z = *(unsigned int*)&h2p;
    pk.w = *(unsigned int*)&h3;
    *(uint4*)(h2 + (size_t)n * H + coff) = pk;
  }
}

// ---------------------------------------------------------------------------
// decode (2 pairs/thread): out[p] = sigmoid(dot(h2[s], h2[d]))
// ---------------------------------------------------------------------------
__device__ inline float dot8h(uint4 u, uint4 v) {
  float acc = 0.f;
  const unsigned int* uw = (const unsigned int*)&u;
  const unsigned int* vw = (const unsigned int*)&v;
#pragma unroll
  for (int j = 0; j < 4; ++j) {
    float2 a = __half22float2(*(const __half2*)&uw[j]);
    float2 b = __half22float2(*(const __half2*)&vw[j]);
    acc = fmaf(a.x, b.x, acc);
    acc = fmaf(a.y, b.y, acc);
  }
  return acc;
}

__global__ void __launch_bounds__(256) k_decode(
    const int* __restrict__ ps, const int* __restrict__ pd,
    const __half* __restrict__ h2, float* __restrict__ out, int P) {
  int t = blockIdx.x * 256 + threadIdx.x;
  int p = t * 2;
  if (p >= P) return;
  int2 av = *(const int2*)(ps + p);
  int2 bv = *(const int2*)(pd + p);
  const uint4* ha0 = (const uint4*)(h2 + (size_t)av.x * H);
  const uint4* hb0 = (const uint4*)(h2 + (size_t)bv.x * H);
  const uint4* ha1 = (const uint4*)(h2 + (size_t)av.y * H);
  const uint4* hb1 = (const uint4*)(h2 + (size_t)bv.y * H);
  uint4 u00 = ha0[0], u01 = ha0[1];
  uint4 v00 = hb0[0], v01 = hb0[1];
  uint4 u10 = ha1[0], u11 = ha1[1];
  uint4 v10 = hb1[0], v11 = hb1[1];
  float d0 = dot8h(u00, v00) + dot8h(u01, v01);
  float d1 = dot8h(u10, v10) + dot8h(u11, v11);
  float o0 = 1.f / (1.f + __expf(-d0));
  float o1 = 1.f / (1.f + __expf(-d1));
  if (p + 1 < P) {
    *(float2*)(out + p) = make_float2(o0, o1);
  } else {
    out[p] = o0;
  }
}

// ---------------------------------------------------------------------------
extern "C" void kernel_launch(void* const* d_in, const int* in_sizes, int n_in,
                              void* d_out, int out_size, void* d_ws, size_t ws_size,
                              hipStream_t stream) {
  const float* x   = (const float*)d_in[0];
  const float* W1l = (const float*)d_in[1];
  const float* b1  = (const float*)d_in[2];
  const float* W1r = (const float*)d_in[3];
  const float* W2l = (const float*)d_in[4];
  const float* b2  = (const float*)d_in[5];
  const float* W2r = (const float*)d_in[6];
  const int* ei = (const int*)d_in[7];  // [2, E] int32
  const int* di = (const int*)d_in[8];  // [2, P] int32
  const int E = in_sizes[7] / 2;
  const int P = in_sizes[8] / 2;

  const size_t NF = (size_t)N_NODES * H;
  // Gathered tables (3.2 MB each, L2-resident): y1l/z2l int16 fixed-point,
  // h2 fp16. h2 aliases y1l (dead after k_agg1 — k_agg2 reads only z2l/z2r).
  // y1r fp32 aliases z2r (same thread + same element, read-then-write).
  unsigned short* y1l = (unsigned short*)d_ws;   // NF
  __half*         h2  = (__half*)y1l;            // alias
  unsigned short* z2l = y1l + NF;                // NF
  float*  y1r = (float*)(z2l + NF);              // NF floats
  float*  z2r = y1r;                             // alias
  int* recs   = (int*)(y1r + NF);                // NBIN * BINCAP
  int* binCur = recs + (size_t)NBIN * BINCAP;    // NBIN (padded to 512)

  const int lin1Blocks = (N_NODES + 63) / 64;    // 64 nodes per 256-thr block
  const int fillBlocks = (E + ECHUNK - 1) / ECHUNK;
  const int decodeBlocks = ((P + 1) / 2 + 255) / 256;     // 2 pairs/thread

  k_init<<<1, 512, 0, stream>>>(binCur);
  k_lin1<<<lin1Blocks, 256, 0, stream>>>(x, W1l, W1r, y1l, y1r);
  k_binfill<<<fillBlocks, 512, 0, stream>>>(ei, ei + E, binCur, recs, E);
  k_agg1<<<NBIN, 512, 0, stream>>>(recs, binCur, y1l, y1r, b1, W2l, W2r,
                                   z2l, z2r);
  k_agg2<<<NBIN, 512, 0, stream>>>(recs, binCur, z2l, z2r, b2, h2);
  k_decode<<<decodeBlocks, 256, 0, stream>>>(di, di + P, h2, (float*)d_out, P);
}

// Round 2
// 197.558 us; speedup vs baseline: 1.0863x; 1.0482x over previous
//
#include <hip/hip_runtime.h>
#include <hip/hip_fp16.h>

#define N_NODES 100000
#define F_IN 128
#define H 16
#define NBIN 391           // ceil(N_NODES/256); bin b owns nodes [b*256, b*256+256)
#define BINCAP 4608        // per-bin record capacity (mean 4096, +8 sigma)
#define ECHUNK 8192        // edges per binfill block (512 thr x 16)
#define QSCALE 4096.0f     // int16 fixed-point scale (range ±8, err 1.2e-4)
#define QINV (1.0f / 4096.0f)

// Pack two floats to int16 fixed-point (round-nearest, clamped)
__device__ inline unsigned int packi16(float a, float b) {
  int ia = __float2int_rn(fminf(fmaxf(a * QSCALE, -32767.f), 32767.f));
  int ib = __float2int_rn(fminf(fmaxf(b * QSCALE, -32767.f), 32767.f));
  return (unsigned int)((ia & 0xffff) | (ib << 16));
}

// Pack a uint holding two int16 channels into a bias-offset u64 addend:
// low 32 = (lo_i16 + 32768), high 32 = (hi_i16 + 32768). For two's-complement
// 16-bit x, x + 32768 == x ^ 0x8000 (unsigned) — exact, branchless.
// Accumulated sums stay < 2^28 per half (65535 * BINCAP) -> no carry across
// the 32-bit boundary, so one u64 LDS atomic adds BOTH channels exactly.
__device__ inline unsigned long long pk64(unsigned int w) {
  return ((unsigned long long)((w >> 16) ^ 0x8000u) << 32)
       | (unsigned long long)((w & 0xffffu) ^ 0x8000u);
}

// ---------------------------------------------------------------------------
// k_init: binCur[b] = b * BINCAP  (record-region cursors)
// ---------------------------------------------------------------------------
__global__ void __launch_bounds__(512) k_init(int* __restrict__ binCur) {
  int t = threadIdx.x;
  if (t < NBIN) binCur[t] = t * BINCAP;
}

// ---------------------------------------------------------------------------
// k_front: fused lin1 + binfill (disjoint data -> safe in one launch; saves a
// dispatch gap and overlaps binfill's L2-atomic/scatter latency under lin1's
// 51 MB HBM stream). Binfill blocks first in the grid so they start early.
//
// binfill role (b < fillB): radix pass — bin records (src<<8 | dstLow) by
// dst>>8. Record ORDER nondeterministic; record SET deterministic — fine,
// downstream accumulation is integer (order-invariant).
//
// lin1 role: y1l = i16fx(x @ W1l), y1r = x @ W1r. 512 thr = 2 independent
// 256-thr groups x 64 nodes (128 nodes/block); within a group, wave w holds
// K-quarter w (wave-uniform -> W scalar-loaded, K$-resident -> FMA-bound).
// Waves 1-3 of each group write partials to LDS; wave 0 reduces in FIXED
// source order ((p0+p1)+p2)+p3 -> bit-identical to previous version.
// ---------------------------------------------------------------------------
__global__ void __launch_bounds__(512) k_front(
    const float* __restrict__ x, const float* __restrict__ W1l,
    const float* __restrict__ W1r, unsigned short* __restrict__ y1l,
    float* __restrict__ y1r,
    const int* __restrict__ src, const int* __restrict__ dst,
    int* __restrict__ binCur, int* __restrict__ recs, int E, int fillB) {
  __shared__ __align__(16) char smem[49152];   // union: binfill 6 KB | lin1 48 KB
  int t = threadIdx.x;
  int b = blockIdx.x;
  if (b < fillB) {
    // ---------------- binfill role ----------------
    int* hist = (int*)smem;
    int* gbase = hist + 512;
    int* cnt2 = gbase + 512;
    hist[t] = 0;
    cnt2[t] = 0;
    __syncthreads();
    int base = b * ECHUNK;
    int rec[16], bin[16];
#pragma unroll
    for (int j = 0; j < 16; ++j) {
      int e = base + j * 512 + t;
      if (e < E) {
        int s = src[e];
        int d = dst[e];
        rec[j] = (s << 8) | (d & 255);
        bin[j] = d >> 8;
        atomicAdd(&hist[bin[j]], 1);
      } else {
        bin[j] = -1;
      }
    }
    __syncthreads();
    if (t < NBIN) {
      int c = hist[t];
      gbase[t] = (c > 0) ? atomicAdd(&binCur[t], c) : 0;
    }
    __syncthreads();
#pragma unroll
    for (int j = 0; j < 16; ++j) {
      if (bin[j] >= 0) {
        int loc = atomicAdd(&cnt2[bin[j]], 1);
        int slot = gbase[bin[j]] + loc;
        if (slot < (bin[j] + 1) * BINCAP)  // safety clamp (never expected)
          recs[slot] = rec[j];
      }
    }
  } else {
    // ---------------- lin1 role ----------------
    int lb = b - fillB;
    int wid = __builtin_amdgcn_readfirstlane(t >> 6);  // wave 0..7
    int part = wid & 3;                                // K-quarter
    int g = wid >> 2;                                  // node-group 0/1
    int ln = t & 63;
    int n = lb * 128 + g * 64 + ln;
    int nc = (n < N_NODES) ? n : (N_NODES - 1);        // clamp; stores guarded
    float* red = (float*)smem + g * 6144;              // 24 KB per group
    const float4* xr = (const float4*)(x + (size_t)nc * F_IN + part * (F_IN / 4));
    float4 xv[8];
#pragma unroll
    for (int j = 0; j < 8; ++j) xv[j] = xr[j];
    const float* Wl = W1l + part * (F_IN / 4) * H;     // SGPR base, 2 KB
    const float* Wr = W1r + part * (F_IN / 4) * H;
    float al[H], ar[H];
#pragma unroll
    for (int c = 0; c < H; ++c) { al[c] = 0.f; ar[c] = 0.f; }
#pragma unroll
    for (int j = 0; j < 8; ++j) {
      float xs[4] = {xv[j].x, xv[j].y, xv[j].z, xv[j].w};
#pragma unroll
      for (int jj = 0; jj < 4; ++jj) {
        int k = j * 4 + jj;
#pragma unroll
        for (int c = 0; c < H; ++c) {
          al[c] = fmaf(xs[jj], Wl[k * H + c], al[c]);
          ar[c] = fmaf(xs[jj], Wr[k * H + c], ar[c]);
        }
      }
    }
    if (part != 0) {
      int base = (part - 1) * 2048;
#pragma unroll
      for (int c = 0; c < H; ++c) {
        red[base + c * 64 + ln] = al[c];
        red[base + (H + c) * 64 + ln] = ar[c];
      }
    }
    __syncthreads();
    if (part == 0 && n < N_NODES) {
#pragma unroll
      for (int c = 0; c < H; ++c) {
        al[c] = ((al[c] + red[c * 64 + ln]) + red[2048 + c * 64 + ln])
                + red[4096 + c * 64 + ln];
        ar[c] = ((ar[c] + red[(H + c) * 64 + ln]) + red[2048 + (H + c) * 64 + ln])
                + red[4096 + (H + c) * 64 + ln];
      }
      uint4 w0, w1;
      w0.x = packi16(al[0], al[1]);  w0.y = packi16(al[2], al[3]);
      w0.z = packi16(al[4], al[5]);  w0.w = packi16(al[6], al[7]);
      w1.x = packi16(al[8], al[9]);  w1.y = packi16(al[10], al[11]);
      w1.z = packi16(al[12], al[13]); w1.w = packi16(al[14], al[15]);
      uint4* ol = (uint4*)(y1l + (size_t)n * H);   // 32 B row
      ol[0] = w0;
      ol[1] = w1;
      float4* orr = (float4*)(y1r + (size_t)n * H);
#pragma unroll
      for (int q = 0; q < 4; ++q)
        orr[q] = make_float4(ar[4 * q], ar[4 * q + 1], ar[4 * q + 2], ar[4 * q + 3]);
    }
  }
}

// ---------------------------------------------------------------------------
// k_agg1: per-bin edge-parallel conv1 aggregation + epilogue.
// One block per bin (391 x 512 thr). Streams the bin's records (coalesced),
// gathers y1l[src] (32B, L2-resident), accumulates into LDS acc64[pair][node]
// via u64 ds-atomics: 8 value atomics + 1 cnt per record (was 17 u32 — the
// LDS pipe is the serializer, so instruction count is the cost).
// Deterministic (integer, order-invariant). Degree = LDS counter.
// Epilogue: h1 = relu(mean + b1 + y1r) -> LDS; z2 = h1 @ W2{l,r} with W2
// staged in LDS (wave-uniform broadcast reads). FMA order over k = 0..15
// matches the previous version bit-for-bit.
// ---------------------------------------------------------------------------
__global__ void __launch_bounds__(512) k_agg1(
    const int* __restrict__ recs, const int* __restrict__ binCur,
    const unsigned short* __restrict__ y1l, const float* __restrict__ y1r,
    const float* __restrict__ b1, const float* __restrict__ W2l,
    const float* __restrict__ W2r, unsigned short* __restrict__ z2l,
    float* __restrict__ z2r) {
  __shared__ unsigned long long acc[8][256];  // 16 KB: pair p = ch(2p, 2p+1)
  __shared__ int cnt[256];                    // 1 KB
  __shared__ float hf[16][256];               // 16 KB (h1, [ch][node])
  __shared__ float w2l[256];                  // 1 KB
  __shared__ float w2r[256];                  // 1 KB
  int t = threadIdx.x;
  int b = blockIdx.x;
#pragma unroll
  for (int j = 0; j < 4; ++j) ((unsigned long long*)acc)[j * 512 + t] = 0ULL;
  if (t < 256) { cnt[t] = 0; w2l[t] = W2l[t]; }
  else         w2r[t - 256] = W2r[t - 256];
  __syncthreads();
  int rbase = b * BINCAP;
  int R = binCur[b] - rbase;
  if (R > BINCAP) R = BINCAP;
  int rr[9];
#pragma unroll
  for (int j = 0; j < 9; ++j) {
    int idx = j * 512 + t;
    rr[j] = (idx < R) ? recs[rbase + idx] : -1;
  }
  uint4 va[9], vb[9];
#pragma unroll
  for (int j = 0; j < 9; ++j) {
    int s = (rr[j] >= 0) ? (rr[j] >> 8) : 0;
    const uint4* yp = (const uint4*)(y1l + (size_t)s * H);
    va[j] = yp[0];
    vb[j] = yp[1];
  }
#pragma unroll
  for (int j = 0; j < 9; ++j) {
    if (rr[j] >= 0) {
      int nb = rr[j] & 255;
      uint4 v0 = va[j], v1 = vb[j];
      atomicAdd(&cnt[nb], 1);
      atomicAdd(&acc[0][nb], pk64(v0.x));
      atomicAdd(&acc[1][nb], pk64(v0.y));
      atomicAdd(&acc[2][nb], pk64(v0.z));
      atomicAdd(&acc[3][nb], pk64(v0.w));
      atomicAdd(&acc[4][nb], pk64(v1.x));
      atomicAdd(&acc[5][nb], pk64(v1.y));
      atomicAdd(&acc[6][nb], pk64(v1.z));
      atomicAdd(&acc[7][nb], pk64(v1.w));
    }
  }
  __syncthreads();
  // ---- epilogue: thread (node = t>>1, half = t&1) owns 8 channels ----
  int node = t >> 1;
  int half = t & 1;
  int coff = half * 8;
  int n = (b << 8) + node;
  if (n < N_NODES) {
    int dg = cnt[node];
    unsigned int bias = (unsigned int)dg << 15;   // undo per-add +32768 offset
    float s = QINV / fmaxf((float)dg, 1.f);
    const float4* yrp = (const float4*)(y1r + (size_t)n * H + coff);
    float4 y0 = yrp[0], y1v = yrp[1];
    const float4* bp = (const float4*)(b1 + coff);
    float4 b0 = bp[0], b1v = bp[1];
    float yv[8] = {y0.x, y0.y, y0.z, y0.w, y1v.x, y1v.y, y1v.z, y1v.w};
    float bv[8] = {b0.x, b0.y, b0.z, b0.w, b1v.x, b1v.y, b1v.z, b1v.w};
    int ia[8];
#pragma unroll
    for (int p = 0; p < 4; ++p) {
      unsigned long long a = acc[half * 4 + p][node];
      ia[2 * p]     = (int)((unsigned int)a - bias);
      ia[2 * p + 1] = (int)((unsigned int)(a >> 32) - bias);
    }
#pragma unroll
    for (int c = 0; c < 8; ++c) {
      float h = fmaf((float)ia[c], s, bv[c] + yv[c]);
      hf[coff + c][node] = fmaxf(h, 0.f);
    }
  } else {
#pragma unroll
    for (int c = 0; c < 8; ++c) hf[coff + c][node] = 0.f;
  }
  __syncthreads();
  float zl[8], zr[8];
#pragma unroll
  for (int c = 0; c < 8; ++c) { zl[c] = 0.f; zr[c] = 0.f; }
#pragma unroll
  for (int k = 0; k < 16; ++k) {
    float hk = hf[k][node];
#pragma unroll
    for (int c = 0; c < 8; ++c) {
      zl[c] = fmaf(hk, w2l[k * 16 + coff + c], zl[c]);
      zr[c] = fmaf(hk, w2r[k * 16 + coff + c], zr[c]);
    }
  }
  if (n < N_NODES) {
    uint4 pk;
    pk.x = packi16(zl[0], zl[1]);
    pk.y = packi16(zl[2], zl[3]);
    pk.z = packi16(zl[4], zl[5]);
    pk.w = packi16(zl[6], zl[7]);
    *(uint4*)(z2l + (size_t)n * H + coff) = pk;
    float4* zp = (float4*)(z2r + (size_t)n * H + coff);
    zp[0] = make_float4(zr[0], zr[1], zr[2], zr[3]);
    zp[1] = make_float4(zr[4], zr[5], zr[6], zr[7]);
  }
}

// ---------------------------------------------------------------------------
// k_agg2: per-bin edge-parallel conv2 aggregation (u64 atomics, same scheme).
// h2 = fp16(mean(z2l_nbrs) + b2 + z2r).
// ---------------------------------------------------------------------------
__global__ void __launch_bounds__(512) k_agg2(
    const int* __restrict__ recs, const int* __restrict__ binCur,
    const unsigned short* __restrict__ z2l, const float* __restrict__ z2r,
    const float* __restrict__ b2, __half* __restrict__ h2) {
  __shared__ unsigned long long acc[8][256];
  __shared__ int cnt[256];
  int t = threadIdx.x;
  int b = blockIdx.x;
#pragma unroll
  for (int j = 0; j < 4; ++j) ((unsigned long long*)acc)[j * 512 + t] = 0ULL;
  if (t < 256) cnt[t] = 0;
  __syncthreads();
  int rbase = b * BINCAP;
  int R = binCur[b] - rbase;
  if (R > BINCAP) R = BINCAP;
  int rr[9];
#pragma unroll
  for (int j = 0; j < 9; ++j) {
    int idx = j * 512 + t;
    rr[j] = (idx < R) ? recs[rbase + idx] : -1;
  }
  uint4 va[9], vb[9];
#pragma unroll
  for (int j = 0; j < 9; ++j) {
    int s = (rr[j] >= 0) ? (rr[j] >> 8) : 0;
    const uint4* yp = (const uint4*)(z2l + (size_t)s * H);
    va[j] = yp[0];
    vb[j] = yp[1];
  }
#pragma unroll
  for (int j = 0; j < 9; ++j) {
    if (rr[j] >= 0) {
      int nb = rr[j] & 255;
      uint4 v0 = va[j], v1 = vb[j];
      atomicAdd(&cnt[nb], 1);
      atomicAdd(&acc[0][nb], pk64(v0.x));
      atomicAdd(&acc[1][nb], pk64(v0.y));
      atomicAdd(&acc[2][nb], pk64(v0.z));
      atomicAdd(&acc[3][nb], pk64(v0.w));
      atomicAdd(&acc[4][nb], pk64(v1.x));
      atomicAdd(&acc[5][nb], pk64(v1.y));
      atomicAdd(&acc[6][nb], pk64(v1.z));
      atomicAdd(&acc[7][nb], pk64(v1.w));
    }
  }
  __syncthreads();
  int node = t >> 1;
  int half = t & 1;
  int coff = half * 8;
  int n = (b << 8) + node;
  if (n < N_NODES) {
    int dg = cnt[node];
    unsigned int bias = (unsigned int)dg << 15;
    float s = QINV / fmaxf((float)dg, 1.f);
    const float4* zrp = (const float4*)(z2r + (size_t)n * H + coff);
    float4 z0 = zrp[0], z1 = zrp[1];
    const float4* bp = (const float4*)(b2 + coff);
    float4 b0 = bp[0], b1v = bp[1];
    float zv[8] = {z0.x, z0.y, z0.z, z0.w, z1.x, z1.y, z1.z, z1.w};
    float bv[8] = {b0.x, b0.y, b0.z, b0.w, b1v.x, b1v.y, b1v.z, b1v.w};
    int ia[8];
#pragma unroll
    for (int p = 0; p < 4; ++p) {
      unsigned long long a = acc[half * 4 + p][node];
      ia[2 * p]     = (int)((unsigned int)a - bias);
      ia[2 * p + 1] = (int)((unsigned int)(a >> 32) - bias);
    }
    float v[8];
#pragma unroll
    for (int c = 0; c < 8; ++c)
      v[c] = fmaf((float)ia[c], s, bv[c] + zv[c]);
    __half2 h0 = __floats2half2_rn(v[0], v[1]);
    __half2 h1 = __floats2half2_rn(v[2], v[3]);
    __half2 h2p = __floats2half2_rn(v[4], v[5]);
    __half2 h3 = __floats2half2_rn(v[6], v[7]);
    uint4 pk;
    pk.x = *(unsigned int*)&h0;
    pk.y = *(unsigned int*)&h1;
    pk.z = *(unsigned int*)&h2p;
    pk.w = *(unsigned int*)&h3;
    *(uint4*)(h2 + (size_t)n * H + coff) = pk;
  }
}

// ---------------------------------------------------------------------------
// decode (2 pairs/thread): out[p] = sigmoid(dot(h2[s], h2[d]))
// ---------------------------------------------------------------------------
__device__ inline float dot8h(uint4 u, uint4 v) {
  float acc = 0.f;
  const unsigned int* uw = (const unsigned int*)&u;
  const unsigned int* vw = (const unsigned int*)&v;
#pragma unroll
  for (int j = 0; j < 4; ++j) {
    float2 a = __half22float2(*(const __half2*)&uw[j]);
    float2 b = __half22float2(*(const __half2*)&vw[j]);
    acc = fmaf(a.x, b.x, acc);
    acc = fmaf(a.y, b.y, acc);
  }
  return acc;
}

__global__ void __launch_bounds__(256) k_decode(
    const int* __restrict__ ps, const int* __restrict__ pd,
    const __half* __restrict__ h2, float* __restrict__ out, int P) {
  int t = blockIdx.x * 256 + threadIdx.x;
  int p = t * 2;
  if (p >= P) return;
  int2 av = *(const int2*)(ps + p);
  int2 bv = *(const int2*)(pd + p);
  const uint4* ha0 = (const uint4*)(h2 + (size_t)av.x * H);
  const uint4* hb0 = (const uint4*)(h2 + (size_t)bv.x * H);
  const uint4* ha1 = (const uint4*)(h2 + (size_t)av.y * H);
  const uint4* hb1 = (const uint4*)(h2 + (size_t)bv.y * H);
  uint4 u00 = ha0[0], u01 = ha0[1];
  uint4 v00 = hb0[0], v01 = hb0[1];
  uint4 u10 = ha1[0], u11 = ha1[1];
  uint4 v10 = hb1[0], v11 = hb1[1];
  float d0 = dot8h(u00, v00) + dot8h(u01, v01);
  float d1 = dot8h(u10, v10) + dot8h(u11, v11);
  float o0 = 1.f / (1.f + __expf(-d0));
  float o1 = 1.f / (1.f + __expf(-d1));
  if (p + 1 < P) {
    *(float2*)(out + p) = make_float2(o0, o1);
  } else {
    out[p] = o0;
  }
}

// ---------------------------------------------------------------------------
extern "C" void kernel_launch(void* const* d_in, const int* in_sizes, int n_in,
                              void* d_out, int out_size, void* d_ws, size_t ws_size,
                              hipStream_t stream) {
  const float* x   = (const float*)d_in[0];
  const float* W1l = (const float*)d_in[1];
  const float* b1  = (const float*)d_in[2];
  const float* W1r = (const float*)d_in[3];
  const float* W2l = (const float*)d_in[4];
  const float* b2  = (const float*)d_in[5];
  const float* W2r = (const float*)d_in[6];
  const int* ei = (const int*)d_in[7];  // [2, E] int32
  const int* di = (const int*)d_in[8];  // [2, P] int32
  const int E = in_sizes[7] / 2;
  const int P = in_sizes[8] / 2;

  const size_t NF = (size_t)N_NODES * H;
  // Gathered tables (3.2 MB each, L2-resident): y1l/z2l int16 fixed-point,
  // h2 fp16. h2 aliases y1l (dead after k_agg1 — k_agg2 reads only z2l/z2r).
  // y1r fp32 aliases z2r (same thread + same element, read-then-write).
  unsigned short* y1l = (unsigned short*)d_ws;   // NF
  __half*         h2  = (__half*)y1l;            // alias
  unsigned short* z2l = y1l + NF;                // NF
  float*  y1r = (float*)(z2l + NF);              // NF floats
  float*  z2r = y1r;                             // alias
  int* recs   = (int*)(y1r + NF);                // NBIN * BINCAP
  int* binCur = recs + (size_t)NBIN * BINCAP;    // NBIN (padded to 512)

  const int fillB = (E + ECHUNK - 1) / ECHUNK;            // 196
  const int lin1B = (N_NODES + 127) / 128;                // 782 (128 nodes/blk)
  const int decodeBlocks = ((P + 1) / 2 + 255) / 256;     // 2 pairs/thread

  k_init<<<1, 512, 0, stream>>>(binCur);
  k_front<<<fillB + lin1B, 512, 0, stream>>>(x, W1l, W1r, y1l, y1r,
                                             ei, ei + E, binCur, recs, E, fillB);
  k_agg1<<<NBIN, 512, 0, stream>>>(recs, binCur, y1l, y1r, b1, W2l, W2r,
                                   z2l, z2r);
  k_agg2<<<NBIN, 512, 0, stream>>>(recs, binCur, z2l, z2r, b2, h2);
  k_decode<<<decodeBlocks, 256, 0, stream>>>(di, di + P, h2, (float*)d_out, P);
}